// Round 1
// baseline (183.282 us; speedup 1.0000x reference)
//
#include <hip/hip_runtime.h>

#define N 2048
#define T 32
#define D 128
#define BT 64      // pair-tile edge
#define STR 36     // padded LDS row stride (32 data + 4 pad) — breaks bank alignment

// ---------------------------------------------------------------------------
// Kernel 1: rnorm[i] = 1/||X[i]|| . One wave per row (4 rows / 256-thread block).
// ---------------------------------------------------------------------------
__global__ __launch_bounds__(256) void rnorm_kernel(const float* __restrict__ X,
                                                    float* __restrict__ rnorm) {
  int row  = blockIdx.x * 4 + (threadIdx.x >> 6);
  int lane = threadIdx.x & 63;
  const float2* xr = (const float2*)(X + (size_t)row * D);
  float2 v = xr[lane];                       // 2 floats/lane * 64 lanes = 128
  float ss = v.x * v.x + v.y * v.y;
#pragma unroll
  for (int off = 32; off > 0; off >>= 1) ss += __shfl_xor(ss, off, 64);
  if (lane == 0) rnorm[row] = rsqrtf(ss);
}

// ---------------------------------------------------------------------------
// Kernel 2: fused pair tile. Block = 256 threads = 16x16 thread grid, each
// thread owns a 4x4 pair micro-tile of a 64x64 tile. Upper-triangular grid.
// ---------------------------------------------------------------------------
__global__ __launch_bounds__(256, 4) void pair_kernel(
    const float* __restrict__ pred,     // [N][T]
    const float* __restrict__ X,        // [N][D]
    const float* __restrict__ rnorm,    // [N]
    const float* __restrict__ scale_p,  // [1]
    double* __restrict__ acc) {
  int a = blockIdx.y, b = blockIdx.x;
  if (b < a) return;                    // below-diagonal tiles contribute nothing

  __shared__ float As[BT * STR], Bs[BT * STR];  // X chunks (normalized)
  __shared__ float Pa[BT * STR], Pb[BT * STR];  // prediction rows
  __shared__ double red[4];

  const int tid   = threadIdx.x;
  const int aRow0 = a * BT, bRow0 = b * BT;
  const int srow  = tid >> 2;           // staging row 0..63
  const int sc    = (tid & 3) << 2;     // staging col {0,4,8,12}
  const float ra  = rnorm[aRow0 + srow];
  const float rb  = rnorm[bRow0 + srow];
  const float scale = scale_p[0];

  // ---- stage predictions once (32 floats/row; 2 float4 per thread per tile)
  {
    const float* pa = pred + (size_t)(aRow0 + srow) * T;
    const float* pb = pred + (size_t)(bRow0 + srow) * T;
    float4 v0 = *(const float4*)(pa + sc);
    float4 v1 = *(const float4*)(pa + sc + 16);
    float4 w0 = *(const float4*)(pb + sc);
    float4 w1 = *(const float4*)(pb + sc + 16);
    *(float4*)(&Pa[srow * STR + sc])      = v0;
    *(float4*)(&Pa[srow * STR + sc + 16]) = v1;
    *(float4*)(&Pb[srow * STR + sc])      = w0;
    *(float4*)(&Pb[srow * STR + sc + 16]) = w1;
  }

  const int tx = tid & 15, ty = tid >> 4;

  float dot[4][4];
#pragma unroll
  for (int i = 0; i < 4; ++i)
#pragma unroll
    for (int l = 0; l < 4; ++l) dot[i][l] = 0.0f;

  // ---- K loop: 4 stages of 32 features each
  for (int dc = 0; dc < 4; ++dc) {
    __syncthreads();  // previous stage's reads done before overwrite
    {
      const float* xa = X + (size_t)(aRow0 + srow) * D + dc * 32;
      const float* xb = X + (size_t)(bRow0 + srow) * D + dc * 32;
      float4 v0 = *(const float4*)(xa + sc);
      float4 v1 = *(const float4*)(xa + sc + 16);
      float4 w0 = *(const float4*)(xb + sc);
      float4 w1 = *(const float4*)(xb + sc + 16);
      v0.x *= ra; v0.y *= ra; v0.z *= ra; v0.w *= ra;
      v1.x *= ra; v1.y *= ra; v1.z *= ra; v1.w *= ra;
      w0.x *= rb; w0.y *= rb; w0.z *= rb; w0.w *= rb;
      w1.x *= rb; w1.y *= rb; w1.z *= rb; w1.w *= rb;
      *(float4*)(&As[srow * STR + sc])      = v0;
      *(float4*)(&As[srow * STR + sc + 16]) = v1;
      *(float4*)(&Bs[srow * STR + sc])      = w0;
      *(float4*)(&Bs[srow * STR + sc + 16]) = w1;
    }
    __syncthreads();
#pragma unroll
    for (int d4 = 0; d4 < 8; ++d4) {
      float4 a4[4], b4[4];
#pragma unroll
      for (int i = 0; i < 4; ++i) {
        a4[i] = *(const float4*)(&As[(ty + 16 * i) * STR + d4 * 4]);
        b4[i] = *(const float4*)(&Bs[(tx + 16 * i) * STR + d4 * 4]);
      }
#pragma unroll
      for (int i = 0; i < 4; ++i)
#pragma unroll
        for (int l = 0; l < 4; ++l)
          dot[i][l] += a4[i].x * b4[l].x + a4[i].y * b4[l].y +
                       a4[i].z * b4[l].z + a4[i].w * b4[l].w;
    }
  }

  // ---- hinge phase: sd = scale*(1-dot); sum_t max(0, |dp| - sd)
  float sd[4][4], ps[4][4];
#pragma unroll
  for (int i = 0; i < 4; ++i)
#pragma unroll
    for (int l = 0; l < 4; ++l) {
      sd[i][l] = scale * (1.0f - dot[i][l]);
      ps[i][l] = 0.0f;
    }

#pragma unroll
  for (int t4 = 0; t4 < 8; ++t4) {
    float4 qa[4], qb[4];
#pragma unroll
    for (int i = 0; i < 4; ++i) {
      qa[i] = *(const float4*)(&Pa[(ty + 16 * i) * STR + t4 * 4]);
      qb[i] = *(const float4*)(&Pb[(tx + 16 * i) * STR + t4 * 4]);
    }
#pragma unroll
    for (int i = 0; i < 4; ++i)
#pragma unroll
      for (int l = 0; l < 4; ++l) {
        float s = sd[i][l];
        ps[i][l] += fmaxf(0.0f, fabsf(qa[i].x - qb[l].x) - s) +
                    fmaxf(0.0f, fabsf(qa[i].y - qb[l].y) - s) +
                    fmaxf(0.0f, fabsf(qa[i].z - qb[l].z) - s) +
                    fmaxf(0.0f, fabsf(qa[i].w - qb[l].w) - s);
      }
  }

  // ---- triangular mask + reduction
  float tsum = 0.0f;
  const bool offdiag = (b > a);
#pragma unroll
  for (int i = 0; i < 4; ++i)
#pragma unroll
    for (int l = 0; l < 4; ++l) {
      int jy = ty + 16 * i, kx = tx + 16 * l;
      bool valid = offdiag || (kx > jy);
      tsum += valid ? ps[i][l] : 0.0f;
    }

  double dsum = (double)tsum;
#pragma unroll
  for (int off = 32; off > 0; off >>= 1) dsum += __shfl_down(dsum, off, 64);
  int wave = tid >> 6, lane = tid & 63;
  if (lane == 0) red[wave] = dsum;
  __syncthreads();
  if (tid == 0) {
    double s = red[0] + red[1] + red[2] + red[3];
    atomicAdd(acc, s);
  }
}

// ---------------------------------------------------------------------------
// Kernel 3: finalize scalar
// ---------------------------------------------------------------------------
__global__ void finalize_kernel(const double* __restrict__ acc,
                                const float* __restrict__ target,
                                float* __restrict__ out) {
  if (threadIdx.x == 0) {
    double mf = 2.0 * acc[0] / ((double)N * (double)(N - 1) * (double)T);
    double r  = mf - (double)target[0];
    out[0] = (float)(r > 0.0 ? r : 0.0);
  }
}

extern "C" void kernel_launch(void* const* d_in, const int* in_sizes, int n_in,
                              void* d_out, int out_size, void* d_ws, size_t ws_size,
                              hipStream_t stream) {
  const float* target = (const float*)d_in[0];
  const float* pred   = (const float*)d_in[1];
  const float* X      = (const float*)d_in[2];
  // d_in[3] = ntimes (int, ==32, hardcoded); d_in[4] = scale
  const float* scale  = (const float*)d_in[4];

  double* acc  = (double*)d_ws;            // 8B accumulator (16B reserved)
  float* rnorm = (float*)d_ws + 4;         // [N] at 16B offset

  hipMemsetAsync(d_ws, 0, 16, stream);     // zero accumulator (ws is poisoned)
  rnorm_kernel<<<dim3(N / 4), dim3(256), 0, stream>>>(X, rnorm);
  pair_kernel<<<dim3(N / BT, N / BT), dim3(256), 0, stream>>>(pred, X, rnorm,
                                                              scale, acc);
  finalize_kernel<<<dim3(1), dim3(64), 0, stream>>>(acc, target, (float*)d_out);
}

// Round 2
// 105.158 us; speedup vs baseline: 1.7429x; 1.7429x over previous
//
#include <hip/hip_runtime.h>

#define N 2048
#define T 32
#define D 128
#define BT 64      // pair-tile edge
#define MT (N/BT)  // 32 tiles per side
#define NTILES (MT*(MT+1)/2)  // 528 upper-triangular tiles
#define STR 36     // padded LDS row stride (32 data + 4 pad)

// ---------------------------------------------------------------------------
// Kernel 1: rnorm[i] = 1/||X[i]|| . One wave per row (4 rows / 256-thread block).
// ---------------------------------------------------------------------------
__global__ __launch_bounds__(256) void rnorm_kernel(const float* __restrict__ X,
                                                    float* __restrict__ rnorm) {
  int row  = blockIdx.x * 4 + (threadIdx.x >> 6);
  int lane = threadIdx.x & 63;
  const float2* xr = (const float2*)(X + (size_t)row * D);
  float2 v = xr[lane];
  float ss = v.x * v.x + v.y * v.y;
#pragma unroll
  for (int off = 32; off > 0; off >>= 1) ss += __shfl_xor(ss, off, 64);
  if (lane == 0) rnorm[row] = rsqrtf(ss);
}

// ---------------------------------------------------------------------------
// Kernel 2: fused pair tile. Block = 256 threads = 16x16 grid of 4x4 pair
// micro-tiles over a 64x64 tile. 1D triangular grid (no wasted blocks).
// NOTE: __launch_bounds__(256) only — capping to (256,4) forced VGPR=64 and
// caused ~190 MB of scratch spill traffic (R1 counters). LDS already limits
// us to 4 blocks/CU, so freeing the register allocator costs nothing.
// ---------------------------------------------------------------------------
__global__ __launch_bounds__(256) void pair_kernel(
    const float* __restrict__ pred,     // [N][T]
    const float* __restrict__ X,        // [N][D]
    const float* __restrict__ rnorm,    // [N]
    const float* __restrict__ scale_p,  // [1]
    double* __restrict__ acc) {
  // linear tile id -> (a,b), a<=b, upper triangular over MT x MT tiles
  int t = blockIdx.x;
  int a = (int)((2 * MT + 1 - sqrtf((float)((2 * MT + 1) * (2 * MT + 1) - 8 * t))) * 0.5f);
  // fix-up (float sqrt rounding): base(a) = a*MT - a*(a-1)/2
  while (a > 0 && t < a * MT - a * (a - 1) / 2) --a;
  while (t >= (a + 1) * MT - (a + 1) * a / 2) ++a;
  int b = a + (t - (a * MT - a * (a - 1) / 2));

  __shared__ float As[BT * STR], Bs[BT * STR];  // normalized X chunks
  __shared__ float Pa[BT * STR], Pb[BT * STR];  // prediction rows
  __shared__ double red[4];

  const int tid   = threadIdx.x;
  const int aRow0 = a * BT, bRow0 = b * BT;
  const int srow  = tid >> 2;           // staging row 0..63
  const int sc    = (tid & 3) << 2;     // staging col {0,4,8,12}
  const float ra  = rnorm[aRow0 + srow];
  const float rb  = rnorm[bRow0 + srow];
  const float scale = scale_p[0];

  // ---- stage predictions once (32 floats/row)
  {
    const float* pa = pred + (size_t)(aRow0 + srow) * T;
    const float* pb = pred + (size_t)(bRow0 + srow) * T;
    float4 v0 = *(const float4*)(pa + sc);
    float4 v1 = *(const float4*)(pa + sc + 16);
    float4 w0 = *(const float4*)(pb + sc);
    float4 w1 = *(const float4*)(pb + sc + 16);
    *(float4*)(&Pa[srow * STR + sc])      = v0;
    *(float4*)(&Pa[srow * STR + sc + 16]) = v1;
    *(float4*)(&Pb[srow * STR + sc])      = w0;
    *(float4*)(&Pb[srow * STR + sc + 16]) = w1;
  }

  const int tx = tid & 15, ty = tid >> 4;

  float dot[4][4];
#pragma unroll
  for (int i = 0; i < 4; ++i)
#pragma unroll
    for (int l = 0; l < 4; ++l) dot[i][l] = 0.0f;

  // ---- K loop: 4 stages of 32 features each
  for (int dc = 0; dc < 4; ++dc) {
    __syncthreads();
    {
      const float* xa = X + (size_t)(aRow0 + srow) * D + dc * 32;
      const float* xb = X + (size_t)(bRow0 + srow) * D + dc * 32;
      float4 v0 = *(const float4*)(xa + sc);
      float4 v1 = *(const float4*)(xa + sc + 16);
      float4 w0 = *(const float4*)(xb + sc);
      float4 w1 = *(const float4*)(xb + sc + 16);
      v0.x *= ra; v0.y *= ra; v0.z *= ra; v0.w *= ra;
      v1.x *= ra; v1.y *= ra; v1.z *= ra; v1.w *= ra;
      w0.x *= rb; w0.y *= rb; w0.z *= rb; w0.w *= rb;
      w1.x *= rb; w1.y *= rb; w1.z *= rb; w1.w *= rb;
      *(float4*)(&As[srow * STR + sc])      = v0;
      *(float4*)(&As[srow * STR + sc + 16]) = v1;
      *(float4*)(&Bs[srow * STR + sc])      = w0;
      *(float4*)(&Bs[srow * STR + sc + 16]) = w1;
    }
    __syncthreads();
#pragma unroll
    for (int d4 = 0; d4 < 8; ++d4) {
      float4 a4[4], b4[4];
#pragma unroll
      for (int i = 0; i < 4; ++i) {
        a4[i] = *(const float4*)(&As[(ty + 16 * i) * STR + d4 * 4]);
        b4[i] = *(const float4*)(&Bs[(tx + 16 * i) * STR + d4 * 4]);
      }
#pragma unroll
      for (int i = 0; i < 4; ++i)
#pragma unroll
        for (int l = 0; l < 4; ++l)
          dot[i][l] += a4[i].x * b4[l].x + a4[i].y * b4[l].y +
                       a4[i].z * b4[l].z + a4[i].w * b4[l].w;
    }
  }

  // ---- hinge phase: reuse dot[][] as sd = scale*(1-dot)  (keeps live set small)
  float ps[4][4];
#pragma unroll
  for (int i = 0; i < 4; ++i)
#pragma unroll
    for (int l = 0; l < 4; ++l) {
      dot[i][l] = scale * (1.0f - dot[i][l]);
      ps[i][l]  = 0.0f;
    }

#pragma unroll
  for (int t4 = 0; t4 < 8; ++t4) {
    float4 qa[4], qb[4];
#pragma unroll
    for (int i = 0; i < 4; ++i) {
      qa[i] = *(const float4*)(&Pa[(ty + 16 * i) * STR + t4 * 4]);
      qb[i] = *(const float4*)(&Pb[(tx + 16 * i) * STR + t4 * 4]);
    }
#pragma unroll
    for (int i = 0; i < 4; ++i)
#pragma unroll
      for (int l = 0; l < 4; ++l) {
        float s = dot[i][l];
        ps[i][l] += fmaxf(0.0f, fabsf(qa[i].x - qb[l].x) - s) +
                    fmaxf(0.0f, fabsf(qa[i].y - qb[l].y) - s) +
                    fmaxf(0.0f, fabsf(qa[i].z - qb[l].z) - s) +
                    fmaxf(0.0f, fabsf(qa[i].w - qb[l].w) - s);
      }
  }

  // ---- triangular mask + reduction
  float tsum = 0.0f;
  const bool offdiag = (b > a);
#pragma unroll
  for (int i = 0; i < 4; ++i)
#pragma unroll
    for (int l = 0; l < 4; ++l) {
      int jy = ty + 16 * i, kx = tx + 16 * l;
      bool valid = offdiag || (kx > jy);
      tsum += valid ? ps[i][l] : 0.0f;
    }

  double dsum = (double)tsum;
#pragma unroll
  for (int off = 32; off > 0; off >>= 1) dsum += __shfl_down(dsum, off, 64);
  int wave = tid >> 6, lane = tid & 63;
  if (lane == 0) red[wave] = dsum;
  __syncthreads();
  if (tid == 0) {
    double s = red[0] + red[1] + red[2] + red[3];
    atomicAdd(acc, s);
  }
}

// ---------------------------------------------------------------------------
// Kernel 3: finalize scalar
// ---------------------------------------------------------------------------
__global__ void finalize_kernel(const double* __restrict__ acc,
                                const float* __restrict__ target,
                                float* __restrict__ out) {
  if (threadIdx.x == 0) {
    double mf = 2.0 * acc[0] / ((double)N * (double)(N - 1) * (double)T);
    double r  = mf - (double)target[0];
    out[0] = (float)(r > 0.0 ? r : 0.0);
  }
}

extern "C" void kernel_launch(void* const* d_in, const int* in_sizes, int n_in,
                              void* d_out, int out_size, void* d_ws, size_t ws_size,
                              hipStream_t stream) {
  const float* target = (const float*)d_in[0];
  const float* pred   = (const float*)d_in[1];
  const float* X      = (const float*)d_in[2];
  // d_in[3] = ntimes (int, ==32, hardcoded); d_in[4] = scale
  const float* scale  = (const float*)d_in[4];

  double* acc  = (double*)d_ws;            // 8B accumulator (16B reserved)
  float* rnorm = (float*)d_ws + 4;         // [N] at 16B offset

  hipMemsetAsync(d_ws, 0, 16, stream);
  rnorm_kernel<<<dim3(N / 4), dim3(256), 0, stream>>>(X, rnorm);
  pair_kernel<<<dim3(NTILES), dim3(256), 0, stream>>>(pred, X, rnorm, scale, acc);
  finalize_kernel<<<dim3(1), dim3(64), 0, stream>>>(acc, target, (float*)d_out);
}